// Round 1
// baseline (2215.762 us; speedup 1.0000x reference)
//
#include <hip/hip_runtime.h>

#define BN_EPS 1e-5f

// ---------------------------------------------------------------------------
// Edge-index canonicalization: harness may hand us int32 or raw int64 data.
// If int64 (little-endian, values < 2^31), every odd int32 word is 0.
// ---------------------------------------------------------------------------
__global__ __launch_bounds__(256) void detect_i64_kernel(const int* __restrict__ ei,
                                                         int* __restrict__ flag, int npairs) {
    __shared__ int ok;
    if (threadIdx.x == 0) ok = 1;
    __syncthreads();
    bool bad = false;
    for (int i = threadIdx.x; i < npairs; i += 256)
        bad |= (ei[2 * i + 1] != 0);
    if (bad) ok = 0;
    __syncthreads();
    if (threadIdx.x == 0) *flag = ok;
}

__global__ __launch_bounds__(256) void canon_kernel(const int* __restrict__ ei,
                                                    const int* __restrict__ flag,
                                                    int* __restrict__ canon, int n) {
    int i = blockIdx.x * 256 + threadIdx.x;
    if (i >= n) return;
    int wide = *flag;
    canon[i] = wide ? ei[2 * i] : ei[i];
}

// ---------------------------------------------------------------------------
// Scatter: agg[dst] += relu(x[src] + edge_attr).  32 lanes per edge, float4.
// ---------------------------------------------------------------------------
__global__ __launch_bounds__(256) void scatter_kernel(const float* __restrict__ x,
                                                      const float* __restrict__ ea,
                                                      const int* __restrict__ src,
                                                      const int* __restrict__ dst,
                                                      float* __restrict__ agg, int E) {
    int t = blockIdx.x * 256 + threadIdx.x;
    int e = t >> 5;
    if (e >= E) return;
    int f = t & 31;
    int s = src[e];
    int d = dst[e];
    float4 xv = reinterpret_cast<const float4*>(x + (size_t)s * 128)[f];
    float4 av = reinterpret_cast<const float4*>(ea + (size_t)e * 128)[f];
    float m0 = fmaxf(xv.x + av.x, 0.0f);
    float m1 = fmaxf(xv.y + av.y, 0.0f);
    float m2 = fmaxf(xv.z + av.z, 0.0f);
    float m3 = fmaxf(xv.w + av.w, 0.0f);
    float* dp = agg + (size_t)d * 128 + f * 4;
    unsafeAtomicAdd(dp + 0, m0);
    unsafeAtomicAdd(dp + 1, m1);
    unsafeAtomicAdd(dp + 2, m2);
    unsafeAtomicAdd(dp + 3, m3);
}

// ---------------------------------------------------------------------------
// GEMM  (M x 128) @ (128 x 128) + bias.
// MODE 1: A = x + agg,                      out = acc + b           (pre-BN h)
// MODE 2: A = relu(h*scale + shift),       out = relu(acc + b)     (post-BN)
// Block: 256 threads, 64-row tile, full 128 cols.
// Thread: 4 rows x 8 cols accumulators. W staged in LDS 32-k chunks.
// ---------------------------------------------------------------------------
template <int MODE>
__global__ __launch_bounds__(256) void gemm_kernel(const float* __restrict__ A0,
                                                   const float* __restrict__ A1,
                                                   const float* __restrict__ scale,
                                                   const float* __restrict__ shift,
                                                   const float* __restrict__ W,
                                                   const float* __restrict__ bias,
                                                   float* __restrict__ out, int N) {
    __shared__ float sA[64][132];   // +4 pad breaks bank aliasing on row reads
    __shared__ float sW[32][128];
    int t = threadIdx.x;
    int rbase = blockIdx.x * 64;

    // Stage A tile (with per-mode input transform)
    {
        int colq = t & 31;   // float4 column
        int r0 = t >> 5;     // 0..7
        float4 s4 = make_float4(0.f, 0.f, 0.f, 0.f), sh4 = make_float4(0.f, 0.f, 0.f, 0.f);
        if (MODE == 2) {
            s4 = reinterpret_cast<const float4*>(scale)[colq];
            sh4 = reinterpret_cast<const float4*>(shift)[colq];
        }
#pragma unroll
        for (int it = 0; it < 8; ++it) {
            int r = r0 + it * 8;
            int row = rbase + r;
            float4 v = make_float4(0.f, 0.f, 0.f, 0.f);
            if (row < N) {
                float4 a = reinterpret_cast<const float4*>(A0 + (size_t)row * 128)[colq];
                if (MODE == 1) {
                    float4 b = reinterpret_cast<const float4*>(A1 + (size_t)row * 128)[colq];
                    v.x = a.x + b.x; v.y = a.y + b.y; v.z = a.z + b.z; v.w = a.w + b.w;
                } else {
                    v.x = fmaxf(a.x * s4.x + sh4.x, 0.f);
                    v.y = fmaxf(a.y * s4.y + sh4.y, 0.f);
                    v.z = fmaxf(a.z * s4.z + sh4.z, 0.f);
                    v.w = fmaxf(a.w * s4.w + sh4.w, 0.f);
                }
            }
            *reinterpret_cast<float4*>(&sA[r][colq * 4]) = v;
        }
    }

    float acc[4][8];
#pragma unroll
    for (int r = 0; r < 4; ++r)
#pragma unroll
        for (int c = 0; c < 8; ++c) acc[r][c] = 0.f;

    int cg = t & 15, rg = t >> 4;
    int c0 = cg * 8;

    for (int kc = 0; kc < 4; ++kc) {
        __syncthreads();   // first iter: sA ready-gate; later: sW reuse-gate
#pragma unroll
        for (int pass = 0; pass < 4; ++pass) {
            int kk = (t >> 5) + pass * 8;
            int k = kc * 32 + kk;
            float4 w = reinterpret_cast<const float4*>(W + (size_t)k * 128)[t & 31];
            *reinterpret_cast<float4*>(&sW[kk][(t & 31) * 4]) = w;
        }
        __syncthreads();
#pragma unroll
        for (int kk0 = 0; kk0 < 32; kk0 += 4) {
            float4 a[4];
#pragma unroll
            for (int r = 0; r < 4; ++r)
                a[r] = *reinterpret_cast<const float4*>(&sA[rg * 4 + r][kc * 32 + kk0]);
#pragma unroll
            for (int j = 0; j < 4; ++j) {
                float4 w0 = *reinterpret_cast<const float4*>(&sW[kk0 + j][c0]);
                float4 w1 = *reinterpret_cast<const float4*>(&sW[kk0 + j][c0 + 4]);
#pragma unroll
                for (int r = 0; r < 4; ++r) {
                    float av = (j == 0) ? a[r].x : (j == 1) ? a[r].y : (j == 2) ? a[r].z : a[r].w;
                    acc[r][0] += av * w0.x;
                    acc[r][1] += av * w0.y;
                    acc[r][2] += av * w0.z;
                    acc[r][3] += av * w0.w;
                    acc[r][4] += av * w1.x;
                    acc[r][5] += av * w1.y;
                    acc[r][6] += av * w1.z;
                    acc[r][7] += av * w1.w;
                }
            }
        }
    }

    float4 b0 = reinterpret_cast<const float4*>(bias + c0)[0];
    float4 b1v = reinterpret_cast<const float4*>(bias + c0)[1];
#pragma unroll
    for (int r = 0; r < 4; ++r) {
        int row = rbase + rg * 4 + r;
        if (row >= N) continue;
        float4 o0, o1;
        o0.x = acc[r][0] + b0.x;  o0.y = acc[r][1] + b0.y;
        o0.z = acc[r][2] + b0.z;  o0.w = acc[r][3] + b0.w;
        o1.x = acc[r][4] + b1v.x; o1.y = acc[r][5] + b1v.y;
        o1.z = acc[r][6] + b1v.z; o1.w = acc[r][7] + b1v.w;
        if (MODE == 2) {
            o0.x = fmaxf(o0.x, 0.f); o0.y = fmaxf(o0.y, 0.f);
            o0.z = fmaxf(o0.z, 0.f); o0.w = fmaxf(o0.w, 0.f);
            o1.x = fmaxf(o1.x, 0.f); o1.y = fmaxf(o1.y, 0.f);
            o1.z = fmaxf(o1.z, 0.f); o1.w = fmaxf(o1.w, 0.f);
        }
        float4* op = reinterpret_cast<float4*>(out + (size_t)row * 128 + c0);
        op[0] = o0;
        op[1] = o1;
    }
}

// ---------------------------------------------------------------------------
// Column sum / sum-of-squares over h [N,128]
// ---------------------------------------------------------------------------
__global__ __launch_bounds__(256) void stats_kernel(const float* __restrict__ h,
                                                    float* __restrict__ sum,
                                                    float* __restrict__ sumsq, int N) {
    int col = threadIdx.x & 127;
    int half = threadIdx.x >> 7;
    float s = 0.f, s2 = 0.f;
    for (int row = blockIdx.x * 2 + half; row < N; row += gridDim.x * 2) {
        float v = h[(size_t)row * 128 + col];
        s += v;
        s2 += v * v;
    }
    __shared__ float ls[128], ls2[128];
    if (half == 1) { ls[col] = s; ls2[col] = s2; }
    __syncthreads();
    if (half == 0) {
        s += ls[col];
        s2 += ls2[col];
        unsafeAtomicAdd(&sum[col], s);
        unsafeAtomicAdd(&sumsq[col], s2);
    }
}

__global__ void finalize_kernel(const float* __restrict__ sum, const float* __restrict__ sumsq,
                                const float* __restrict__ gamma, const float* __restrict__ beta,
                                float* __restrict__ scale, float* __restrict__ shift, float invN) {
    int c = threadIdx.x;
    float mean = sum[c] * invN;
    float var = sumsq[c] * invN - mean * mean;
    float inv = rsqrtf(var + BN_EPS);
    float sc = gamma[c] * inv;
    scale[c] = sc;
    shift[c] = beta[c] - mean * sc;
}

// ---------------------------------------------------------------------------
extern "C" void kernel_launch(void* const* d_in, const int* in_sizes, int n_in,
                              void* d_out, int out_size, void* d_ws, size_t ws_size,
                              hipStream_t stream) {
    const float* x     = (const float*)d_in[0];
    const int*   ei    = (const int*)d_in[1];
    const float* ea    = (const float*)d_in[2];
    const float* W1    = (const float*)d_in[3];
    const float* b1    = (const float*)d_in[4];
    const float* gamma = (const float*)d_in[5];
    const float* beta  = (const float*)d_in[6];
    const float* W2    = (const float*)d_in[7];
    const float* b2    = (const float*)d_in[8];

    int N = in_sizes[0] / 128;
    int E = in_sizes[2] / 128;
    int L = in_sizes[3] / (128 * 128);

    size_t NF = (size_t)N * 128;
    float* agg   = (float*)d_ws;
    float* sum   = agg + NF;
    float* sumsq = sum + 128;
    float* scl   = sumsq + 128;
    float* shf   = scl + 128;
    float* h     = shf + 128;          // agg + NF + 512
    float* xbuf  = h + NF;
    int*   canon = (int*)(xbuf + NF);
    int*   flag  = canon + (size_t)2 * E;

    // Canonicalize edge indices (int64-vs-int32 marshalling safety)
    int npairs = (E < 4096) ? E : 4096;
    detect_i64_kernel<<<1, 256, 0, stream>>>(ei, flag, npairs);
    int E2 = 2 * E;
    canon_kernel<<<(E2 + 255) / 256, 256, 0, stream>>>(ei, flag, canon, E2);
    const int* src = canon;
    const int* dst = canon + E;

    int gemmBlocks = (N + 63) / 64;
    const float* xin = x;
    for (int l = 0; l < L; ++l) {
        float* xout = (l == L - 1) ? (float*)d_out : xbuf;
        hipMemsetAsync(agg, 0, (NF + 256) * sizeof(float), stream);  // agg + sum + sumsq
        scatter_kernel<<<(E * 32 + 255) / 256, 256, 0, stream>>>(xin, ea, src, dst, agg, E);
        gemm_kernel<1><<<gemmBlocks, 256, 0, stream>>>(xin, agg, nullptr, nullptr,
                                                       W1 + (size_t)l * 16384, b1 + (size_t)l * 128,
                                                       h, N);
        stats_kernel<<<256, 256, 0, stream>>>(h, sum, sumsq, N);
        finalize_kernel<<<1, 128, 0, stream>>>(sum, sumsq, gamma + (size_t)l * 128,
                                               beta + (size_t)l * 128, scl, shf, 1.0f / (float)N);
        gemm_kernel<2><<<gemmBlocks, 256, 0, stream>>>(h, nullptr, scl, shf,
                                                       W2 + (size_t)l * 16384, b2 + (size_t)l * 128,
                                                       xout, N);
        xin = xout;
    }
}

// Round 2
// 835.171 us; speedup vs baseline: 2.6531x; 2.6531x over previous
//
#include <hip/hip_runtime.h>

#define BN_EPS 1e-5f

// ---------------------------------------------------------------------------
// Edge-index canonicalization: harness may hand us int32 or raw int64 data.
// If int64 (little-endian, values < 2^31), every odd int32 word is 0.
// ---------------------------------------------------------------------------
__global__ __launch_bounds__(256) void detect_i64_kernel(const int* __restrict__ ei,
                                                         int* __restrict__ flag, int npairs) {
    __shared__ int ok;
    if (threadIdx.x == 0) ok = 1;
    __syncthreads();
    bool bad = false;
    for (int i = threadIdx.x; i < npairs; i += 256)
        bad |= (ei[2 * i + 1] != 0);
    if (bad) ok = 0;
    __syncthreads();
    if (threadIdx.x == 0) *flag = ok;
}

__global__ __launch_bounds__(256) void canon_kernel(const int* __restrict__ ei,
                                                    const int* __restrict__ flag,
                                                    int* __restrict__ canon, int n) {
    int i = blockIdx.x * 256 + threadIdx.x;
    if (i >= n) return;
    int wide = *flag;
    canon[i] = wide ? ei[2 * i] : ei[i];
}

// ---------------------------------------------------------------------------
// CSR build over dst (edge topology is layer-invariant: built once per launch)
// ---------------------------------------------------------------------------
__global__ __launch_bounds__(256) void zero_int_kernel(int* __restrict__ p, int n) {
    int i = blockIdx.x * 256 + threadIdx.x;
    if (i < n) p[i] = 0;
}

__global__ __launch_bounds__(256) void hist_kernel(const int* __restrict__ dst,
                                                   int* __restrict__ deg, int E) {
    int e = blockIdx.x * 256 + threadIdx.x;
    if (e >= E) return;
    atomicAdd(&deg[dst[e]], 1);
}

// Single-block exclusive prefix scan over deg[N] -> rowptr[N+1]
__global__ __launch_bounds__(1024) void scan_kernel(const int* __restrict__ deg,
                                                    int* __restrict__ rowptr, int N) {
    __shared__ int part[1024];
    int t = threadIdx.x;
    int chunk = (N + 1023) / 1024;
    int lo = t * chunk;
    int hi = lo + chunk;
    if (lo > N) lo = N;
    if (hi > N) hi = N;
    int s = 0;
    for (int i = lo; i < hi; ++i) s += deg[i];
    part[t] = s;
    __syncthreads();
    for (int off = 1; off < 1024; off <<= 1) {
        int v = (t >= off) ? part[t - off] : 0;
        __syncthreads();
        part[t] += v;
        __syncthreads();
    }
    int run = (t == 0) ? 0 : part[t - 1];
    for (int i = lo; i < hi; ++i) { rowptr[i] = run; run += deg[i]; }
    if (t == 1023) rowptr[N] = run;
}

__global__ __launch_bounds__(256) void copy_int_kernel(const int* __restrict__ a,
                                                       int* __restrict__ b, int n) {
    int i = blockIdx.x * 256 + threadIdx.x;
    if (i < n) b[i] = a[i];
}

// Scatter edge ids + src ids into dst-ordered buckets
__global__ __launch_bounds__(256) void fill_kernel(const int* __restrict__ src,
                                                   const int* __restrict__ dst,
                                                   int* __restrict__ cursor,
                                                   int* __restrict__ ebuf,
                                                   int* __restrict__ sbuf, int E) {
    int e = blockIdx.x * 256 + threadIdx.x;
    if (e >= E) return;
    int d = dst[e];
    int pos = atomicAdd(&cursor[d], 1);
    ebuf[pos] = e;
    sbuf[pos] = src[e];
}

// ---------------------------------------------------------------------------
// Gather-reduce: agg[n] = sum_{e in bucket(n)} relu(x[src_e] + ea[e])
// 32 lanes per node; lane f owns float4 column f. No atomics, writes all rows.
// ---------------------------------------------------------------------------
__global__ __launch_bounds__(256) void gather_kernel(const float* __restrict__ x,
                                                     const float* __restrict__ ea,
                                                     const int* __restrict__ rowptr,
                                                     const int* __restrict__ ebuf,
                                                     const int* __restrict__ sbuf,
                                                     float* __restrict__ agg, int N) {
    int t = blockIdx.x * 256 + threadIdx.x;
    int n = t >> 5;
    if (n >= N) return;
    int f = t & 31;
    int lo = rowptr[n], hi = rowptr[n + 1];
    float4 acc = make_float4(0.f, 0.f, 0.f, 0.f);
    for (int i = lo; i < hi; ++i) {
        int e = ebuf[i];
        int s = sbuf[i];
        float4 xv = reinterpret_cast<const float4*>(x + (size_t)s * 128)[f];
        float4 av = reinterpret_cast<const float4*>(ea + (size_t)e * 128)[f];
        acc.x += fmaxf(xv.x + av.x, 0.f);
        acc.y += fmaxf(xv.y + av.y, 0.f);
        acc.z += fmaxf(xv.z + av.z, 0.f);
        acc.w += fmaxf(xv.w + av.w, 0.f);
    }
    reinterpret_cast<float4*>(agg + (size_t)n * 128)[f] = acc;
}

// ---------------------------------------------------------------------------
// GEMM  (M x 128) @ (128 x 128) + bias.
// MODE 1: A = x + agg,                 out = acc + b           (pre-BN h)
// MODE 2: A = relu(h*scale + shift),   out = relu(acc + b)     (post-BN)
// ---------------------------------------------------------------------------
template <int MODE>
__global__ __launch_bounds__(256) void gemm_kernel(const float* __restrict__ A0,
                                                   const float* __restrict__ A1,
                                                   const float* __restrict__ scale,
                                                   const float* __restrict__ shift,
                                                   const float* __restrict__ W,
                                                   const float* __restrict__ bias,
                                                   float* __restrict__ out, int N) {
    __shared__ float sA[64][132];
    __shared__ float sW[32][128];
    int t = threadIdx.x;
    int rbase = blockIdx.x * 64;

    {
        int colq = t & 31;
        int r0 = t >> 5;
        float4 s4 = make_float4(0.f, 0.f, 0.f, 0.f), sh4 = make_float4(0.f, 0.f, 0.f, 0.f);
        if (MODE == 2) {
            s4 = reinterpret_cast<const float4*>(scale)[colq];
            sh4 = reinterpret_cast<const float4*>(shift)[colq];
        }
#pragma unroll
        for (int it = 0; it < 8; ++it) {
            int r = r0 + it * 8;
            int row = rbase + r;
            float4 v = make_float4(0.f, 0.f, 0.f, 0.f);
            if (row < N) {
                float4 a = reinterpret_cast<const float4*>(A0 + (size_t)row * 128)[colq];
                if (MODE == 1) {
                    float4 b = reinterpret_cast<const float4*>(A1 + (size_t)row * 128)[colq];
                    v.x = a.x + b.x; v.y = a.y + b.y; v.z = a.z + b.z; v.w = a.w + b.w;
                } else {
                    v.x = fmaxf(a.x * s4.x + sh4.x, 0.f);
                    v.y = fmaxf(a.y * s4.y + sh4.y, 0.f);
                    v.z = fmaxf(a.z * s4.z + sh4.z, 0.f);
                    v.w = fmaxf(a.w * s4.w + sh4.w, 0.f);
                }
            }
            *reinterpret_cast<float4*>(&sA[r][colq * 4]) = v;
        }
    }

    float acc[4][8];
#pragma unroll
    for (int r = 0; r < 4; ++r)
#pragma unroll
        for (int c = 0; c < 8; ++c) acc[r][c] = 0.f;

    int cg = t & 15, rg = t >> 4;
    int c0 = cg * 8;

    for (int kc = 0; kc < 4; ++kc) {
        __syncthreads();
#pragma unroll
        for (int pass = 0; pass < 4; ++pass) {
            int kk = (t >> 5) + pass * 8;
            int k = kc * 32 + kk;
            float4 w = reinterpret_cast<const float4*>(W + (size_t)k * 128)[t & 31];
            *reinterpret_cast<float4*>(&sW[kk][(t & 31) * 4]) = w;
        }
        __syncthreads();
#pragma unroll
        for (int kk0 = 0; kk0 < 32; kk0 += 4) {
            float4 a[4];
#pragma unroll
            for (int r = 0; r < 4; ++r)
                a[r] = *reinterpret_cast<const float4*>(&sA[rg * 4 + r][kc * 32 + kk0]);
#pragma unroll
            for (int j = 0; j < 4; ++j) {
                float4 w0 = *reinterpret_cast<const float4*>(&sW[kk0 + j][c0]);
                float4 w1 = *reinterpret_cast<const float4*>(&sW[kk0 + j][c0 + 4]);
#pragma unroll
                for (int r = 0; r < 4; ++r) {
                    float av = (j == 0) ? a[r].x : (j == 1) ? a[r].y : (j == 2) ? a[r].z : a[r].w;
                    acc[r][0] += av * w0.x;
                    acc[r][1] += av * w0.y;
                    acc[r][2] += av * w0.z;
                    acc[r][3] += av * w0.w;
                    acc[r][4] += av * w1.x;
                    acc[r][5] += av * w1.y;
                    acc[r][6] += av * w1.z;
                    acc[r][7] += av * w1.w;
                }
            }
        }
    }

    float4 b0 = reinterpret_cast<const float4*>(bias + c0)[0];
    float4 b1v = reinterpret_cast<const float4*>(bias + c0)[1];
#pragma unroll
    for (int r = 0; r < 4; ++r) {
        int row = rbase + rg * 4 + r;
        if (row >= N) continue;
        float4 o0, o1;
        o0.x = acc[r][0] + b0.x;  o0.y = acc[r][1] + b0.y;
        o0.z = acc[r][2] + b0.z;  o0.w = acc[r][3] + b0.w;
        o1.x = acc[r][4] + b1v.x; o1.y = acc[r][5] + b1v.y;
        o1.z = acc[r][6] + b1v.z; o1.w = acc[r][7] + b1v.w;
        if (MODE == 2) {
            o0.x = fmaxf(o0.x, 0.f); o0.y = fmaxf(o0.y, 0.f);
            o0.z = fmaxf(o0.z, 0.f); o0.w = fmaxf(o0.w, 0.f);
            o1.x = fmaxf(o1.x, 0.f); o1.y = fmaxf(o1.y, 0.f);
            o1.z = fmaxf(o1.z, 0.f); o1.w = fmaxf(o1.w, 0.f);
        }
        float4* op = reinterpret_cast<float4*>(out + (size_t)row * 128 + c0);
        op[0] = o0;
        op[1] = o1;
    }
}

// ---------------------------------------------------------------------------
// Column sum / sum-of-squares over h [N,128]
// ---------------------------------------------------------------------------
__global__ __launch_bounds__(256) void stats_kernel(const float* __restrict__ h,
                                                    float* __restrict__ sum,
                                                    float* __restrict__ sumsq, int N) {
    int col = threadIdx.x & 127;
    int half = threadIdx.x >> 7;
    float s = 0.f, s2 = 0.f;
    for (int row = blockIdx.x * 2 + half; row < N; row += gridDim.x * 2) {
        float v = h[(size_t)row * 128 + col];
        s += v;
        s2 += v * v;
    }
    __shared__ float ls[128], ls2[128];
    if (half == 1) { ls[col] = s; ls2[col] = s2; }
    __syncthreads();
    if (half == 0) {
        s += ls[col];
        s2 += ls2[col];
        unsafeAtomicAdd(&sum[col], s);
        unsafeAtomicAdd(&sumsq[col], s2);
    }
}

__global__ void finalize_kernel(const float* __restrict__ sum, const float* __restrict__ sumsq,
                                const float* __restrict__ gamma, const float* __restrict__ beta,
                                float* __restrict__ scale, float* __restrict__ shift, float invN) {
    int c = threadIdx.x;
    float mean = sum[c] * invN;
    float var = sumsq[c] * invN - mean * mean;
    float inv = rsqrtf(var + BN_EPS);
    float sc = gamma[c] * inv;
    scale[c] = sc;
    shift[c] = beta[c] - mean * sc;
}

// ---------------------------------------------------------------------------
extern "C" void kernel_launch(void* const* d_in, const int* in_sizes, int n_in,
                              void* d_out, int out_size, void* d_ws, size_t ws_size,
                              hipStream_t stream) {
    const float* x     = (const float*)d_in[0];
    const int*   ei    = (const int*)d_in[1];
    const float* ea    = (const float*)d_in[2];
    const float* W1    = (const float*)d_in[3];
    const float* b1    = (const float*)d_in[4];
    const float* gamma = (const float*)d_in[5];
    const float* beta  = (const float*)d_in[6];
    const float* W2    = (const float*)d_in[7];
    const float* b2    = (const float*)d_in[8];

    int N = in_sizes[0] / 128;
    int E = in_sizes[2] / 128;
    int L = in_sizes[3] / (128 * 128);

    size_t NF = (size_t)N * 128;
    float* agg   = (float*)d_ws;
    float* h     = agg + NF;
    float* sum   = h + NF;
    float* sumsq = sum + 128;
    float* scl   = sumsq + 128;
    float* shf   = scl + 128;
    int*   canon  = (int*)(shf + 128);
    int*   flag   = canon + (size_t)2 * E;
    int*   deg    = flag + 1;
    int*   rowptr = deg + N;
    int*   cursor = rowptr + N + 1;
    int*   ebuf   = cursor + N;
    int*   sbuf   = ebuf + E;

    // ---- Canonicalize edge indices (int64-vs-int32 marshalling safety) ----
    int npairs = (E < 4096) ? E : 4096;
    detect_i64_kernel<<<1, 256, 0, stream>>>(ei, flag, npairs);
    int E2 = 2 * E;
    canon_kernel<<<(E2 + 255) / 256, 256, 0, stream>>>(ei, flag, canon, E2);
    const int* src = canon;
    const int* dst = canon + E;

    // ---- Build CSR over dst (once; topology is layer-invariant) ----
    int eBlocks = (E + 255) / 256;
    int nBlocks = (N + 255) / 256;
    zero_int_kernel<<<nBlocks, 256, 0, stream>>>(deg, N);
    hist_kernel<<<eBlocks, 256, 0, stream>>>(dst, deg, E);
    scan_kernel<<<1, 1024, 0, stream>>>(deg, rowptr, N);
    copy_int_kernel<<<nBlocks, 256, 0, stream>>>(rowptr, cursor, N);
    fill_kernel<<<eBlocks, 256, 0, stream>>>(src, dst, cursor, ebuf, sbuf, E);

    // ---- Layers ----
    int gatherBlocks = (N * 32 + 255) / 256;
    int gemmBlocks = (N + 63) / 64;
    const float* xin = x;
    for (int l = 0; l < L; ++l) {
        float* xout = (float*)d_out;   // layer0 intermediate lives in d_out, overwritten by layer1
        gather_kernel<<<gatherBlocks, 256, 0, stream>>>(xin, ea, rowptr, ebuf, sbuf, agg, N);
        gemm_kernel<1><<<gemmBlocks, 256, 0, stream>>>(xin, agg, nullptr, nullptr,
                                                       W1 + (size_t)l * 16384, b1 + (size_t)l * 128,
                                                       h, N);
        hipMemsetAsync(sum, 0, 256 * sizeof(float), stream);
        stats_kernel<<<256, 256, 0, stream>>>(h, sum, sumsq, N);
        finalize_kernel<<<1, 128, 0, stream>>>(sum, sumsq, gamma + (size_t)l * 128,
                                               beta + (size_t)l * 128, scl, shf, 1.0f / (float)N);
        gemm_kernel<2><<<gemmBlocks, 256, 0, stream>>>(h, nullptr, scl, shf,
                                                       W2 + (size_t)l * 16384, b2 + (size_t)l * 128,
                                                       xout, N);
        xin = xout;
    }
}